// Round 1
// baseline (242.315 us; speedup 1.0000x reference)
//
#include <hip/hip_runtime.h>

// Problem constants
#define B_SZ 16
#define CIN  512
#define LIN  1024
#define LP   1022      // L - K + 1
#define HEADS 8
#define DH    64

typedef __attribute__((ext_vector_type(8))) short bf16x8;
typedef __attribute__((ext_vector_type(4))) float f32x4;

__device__ inline unsigned short f2bf(float f) {
    union { float f; unsigned int u; } c; c.f = f;
    unsigned int r = c.u + 0x7FFF + ((c.u >> 16) & 1);   // RNE
    return (unsigned short)(r >> 16);
}

// async global->LDS DMA, 16B per lane, LDS dst = wave-uniform base + lane*16
__device__ __forceinline__ void gl_lds16(const unsigned short* g, unsigned short* l) {
    __builtin_amdgcn_global_load_lds((const __attribute__((address_space(1))) void*)g,
                                     (__attribute__((address_space(3))) void*)l, 16, 0, 0);
}

// XOR swizzle on 16B granules: involution, preserves 8-granule blocks,
// spreads 16 consecutive rows across all 8 bank groups (2-way = free).
#define SWZ(G) ((G) ^ (((G) >> 3) & 7))

// ---------------------------------------------------------------------------
// xb cvt: x fp32 [b][512 i][1024 l] -> xb bf16 [b][1024 l][512 i]
// ---------------------------------------------------------------------------
__global__ __launch_bounds__(256) void xb_cvt_kernel(const float* __restrict__ x,
                                                     unsigned short* __restrict__ xb) {
    __shared__ float sm[64][68];
    const int t  = threadIdx.x;
    const int l0 = blockIdx.x * 64;
    const int i0 = blockIdx.y * 64;
    const int b  = blockIdx.z;
    const float* S = x + ((size_t)b * CIN + i0) * LIN;

    #pragma unroll
    for (int rr = 0; rr < 4; rr++) {
        int idx = rr * 1024 + t * 4;
        int ii = idx >> 6, lj = idx & 63;
        *(float4*)&sm[ii][lj] = *(const float4*)(S + (size_t)ii * LIN + l0 + lj);
    }
    __syncthreads();

    #pragma unroll
    for (int rr = 0; rr < 4; rr++) {
        int idx = rr * 1024 + t * 4;
        int l = idx >> 6, dj = idx & 63;
        ushort4 h;
        h.x = f2bf(sm[dj + 0][l]);
        h.y = f2bf(sm[dj + 1][l]);
        h.z = f2bf(sm[dj + 2][l]);
        h.w = f2bf(sm[dj + 3][l]);
        *(ushort4*)(xb + ((size_t)b * 1024 + l0 + l) * 512 + i0 + dj) = h;
    }
}

// ---------------------------------------------------------------------------
// wb cvt: w_c[o][i][kk] fp32 -> wb bf16 [kk][O=c*512+o][i]
// ---------------------------------------------------------------------------
__global__ __launch_bounds__(256) void wb_cvt_kernel(const float* __restrict__ w0,
                                                     const float* __restrict__ w1,
                                                     const float* __restrict__ w2,
                                                     unsigned short* __restrict__ wb) {
    const int kk = blockIdx.y;
    int flat = blockIdx.x * 256 + threadIdx.x;
    int i  = flat & 511;
    int oG = flat >> 9;
    int c  = oG >> 9, o = oG & 511;
    const float* w = (c == 0) ? w0 : (c == 1) ? w1 : w2;
    wb[(size_t)kk * 786432 + flat] = f2bf(w[o * 1536 + i * 3 + kk]);
}

// ---------------------------------------------------------------------------
// Fused 3-conv bf16 MFMA GEMM with global_load_lds staging + XOR-swizzled LDS.
// (unchanged — at the m97 structural plateau, 822 TF; 8-phase port is next)
// ---------------------------------------------------------------------------
__global__ __launch_bounds__(256) void conv_mfma_kernel(
        const unsigned short* __restrict__ xb,   // [16][1024][512]
        const unsigned short* __restrict__ wb,   // [3][1536][512]
        const float* __restrict__ b0, const float* __restrict__ b1,
        const float* __restrict__ b2,
        unsigned short* __restrict__ Qt, unsigned short* __restrict__ Kt,
        unsigned short* __restrict__ Vt, float qscale) {
    __shared__ unsigned short smem[16896];       // staging 16512 sh | vt 16896 sh
    unsigned short* xs = smem;                   // [132][32]
    unsigned short* ws = smem + 4224;            // [384][32]

    const int t    = threadIdx.x;
    const int wave = t >> 6;
    const int lane = t & 63;
    const int col  = lane & 15;
    const int quad = lane >> 4;
    const int wh   = wave >> 1;                  // o half
    const int wn   = wave & 1;                   // l half
    const int l0   = blockIdx.x * 128;
    const int o0   = blockIdx.y * 128;
    const int b    = blockIdx.z;

    f32x4 acc[4][4];
    #pragma unroll
    for (int i = 0; i < 4; i++)
        #pragma unroll
        for (int j = 0; j < 4; j++) acc[i][j] = (f32x4){0.f, 0.f, 0.f, 0.f};

    const unsigned short* xrow = xb + (size_t)b * 1024 * 512;

    for (int ic = 0; ic < 512; ic += 32) {
        __syncthreads();   // previous chunk's compute done before overwrite

        // ---- W DMA: 24 instrs (16 rows each), this wave does 6 ----
        #pragma unroll
        for (int j = 0; j < 6; j++) {
            int instr = wave * 6 + j;
            int Gg = SWZ(instr * 64 + lane);
            int p = Gg >> 2, q = Gg & 3;
            int kk = p >> 7, orow = p & 127;
            gl_lds16(wb + ((size_t)(kk * 1536 + o0 + orow)) * 512 + ic + q * 8,
                     ws + instr * 512);
        }
        // ---- X DMA: 8 instrs for rows 0..127, this wave does 2 ----
        #pragma unroll
        for (int j = 0; j < 2; j++) {
            int instr = wave * 2 + j;
            int Gg = SWZ(instr * 64 + lane);
            int p = Gg >> 2, q = Gg & 3;
            gl_lds16(xrow + (size_t)(l0 + p) * 512 + ic + q * 8,
                     xs + instr * 512);
        }
        // ---- halo rows 128,129 (checked, zero-fill OOB) ----
        if (t < 8) {
            int row = 128 + (t >> 2), sg = t & 3;
            int gl = l0 + row;
            bf16x8 v = (bf16x8){0, 0, 0, 0, 0, 0, 0, 0};
            if (gl < 1024) v = *(const bf16x8*)(xrow + (size_t)gl * 512 + ic + sg * 8);
            *(bf16x8*)&xs[SWZ(512 + t) * 8] = v;
        }
        __syncthreads();   // drains vmcnt (DMA) + lgkmcnt (halo)

        #pragma unroll
        for (int kk = 0; kk < 3; kk++) {
            bf16x8 af[4], bfr[4];
            #pragma unroll
            for (int ms = 0; ms < 4; ms++) {
                int G = ((kk * 128 + wh * 64 + ms * 16 + col) << 2) | quad;
                af[ms] = *(const bf16x8*)&ws[SWZ(G) * 8];
            }
            #pragma unroll
            for (int ns = 0; ns < 4; ns++) {
                int G = ((wn * 64 + ns * 16 + col + kk) << 2) | quad;
                bfr[ns] = *(const bf16x8*)&xs[SWZ(G) * 8];
            }
            #pragma unroll
            for (int ms = 0; ms < 4; ms++)
                #pragma unroll
                for (int ns = 0; ns < 4; ns++)
                    acc[ms][ns] = __builtin_amdgcn_mfma_f32_16x16x32_bf16(af[ms], bfr[ns], acc[ms][ns], 0, 0, 0);
        }
    }

    const int c = blockIdx.y >> 2;               // which conv (uniform per block)

    if (c < 2) {
        // ---- Q/K epilogue: direct bf16 stores to [bh][l][d] ----
        unsigned short* dst = (c == 0) ? Qt : Kt;
        const float* bias   = (c == 0) ? b0 : b1;
        const float sc      = (c == 0) ? qscale : 1.0f;
        const int h = (((o0 & 511) + wh * 64) >> 6) & 7;
        unsigned short* base = dst + (size_t)(b * 8 + h) * 65536;
        #pragma unroll
        for (int ms = 0; ms < 4; ms++) {
            int ob = (o0 & 511) + wh * 64 + ms * 16 + quad * 4;
            float bv[4];
            #pragma unroll
            for (int r = 0; r < 4; r++) bv[r] = bias[ob + r];
            int d0 = ms * 16 + quad * 4;
            #pragma unroll
            for (int ns = 0; ns < 4; ns++) {
                int l = l0 + wn * 64 + ns * 16 + col;
                ushort4 hv;
                hv.x = f2bf((acc[ms][ns][0] + bv[0]) * sc);
                hv.y = f2bf((acc[ms][ns][1] + bv[1]) * sc);
                hv.z = f2bf((acc[ms][ns][2] + bv[2]) * sc);
                hv.w = f2bf((acc[ms][ns][3] + bv[3]) * sc);
                *(ushort4*)(base + (size_t)l * 64 + d0) = hv;
            }
        }
    } else {
        // ---- V epilogue: LDS transpose then coalesced rows to [bh][d][1024] ----
        __syncthreads();
        unsigned short* vt = smem;               // [128][132]
        #pragma unroll
        for (int ms = 0; ms < 4; ms++) {
            int ob = (o0 & 511) + wh * 64 + ms * 16 + quad * 4;
            #pragma unroll
            for (int ns = 0; ns < 4; ns++) {
                int lc = wn * 64 + ns * 16 + col;
                #pragma unroll
                for (int r = 0; r < 4; r++)
                    vt[(wh * 64 + ms * 16 + quad * 4 + r) * 132 + lc] =
                        f2bf(acc[ms][ns][r] + b2[ob + r]);
            }
        }
        __syncthreads();
        #pragma unroll
        for (int it = 0; it < 8; it++) {
            int flat = it * 2048 + t * 8;
            int row = flat >> 7, colx = flat & 127;
            bf16x8 v = *(const bf16x8*)&vt[row * 132 + colx];
            int og = (o0 & 511) + row;
            int h = og >> 6, d = og & 63;
            *(bf16x8*)(Vt + ((size_t)(b * 8 + h) * 64 + d) * 1024 + l0 + colx) = v;
        }
    }
}

// ---------------------------------------------------------------------------
// Flash attention, bf16 MFMA, no-max softmax (p = 2^s, log2e folded into Q).
// S^T formulation: A=K, B=Q -> P exits with 4 contiguous k per lane
// (packed ds_write_b64), reads back as B-operand for PV (A=V).
//
// Round 6: T3 minimum-2-phase pipeline (double-buffered K/V, issue-early /
// wait-late, ONE raw s_barrier per k-tile — __syncthreads would vmcnt(0)-drain
// the prefetch), T5 setprio around MFMA clusters, XCD-grouping block swizzle
// (8 q-blocks of one bh -> one XCD: per-XCD K/V L2 footprint 32MB -> 4MB).
// LDS: 2x(Ks 8KB + Vs 8KB) dbuf + Ps 18KB = 50KB -> 3 blocks/CU.
// ---------------------------------------------------------------------------
__global__ __launch_bounds__(256, 3) void attn_kernel(
        const unsigned short* __restrict__ Qt,
        const unsigned short* __restrict__ Kt,
        const unsigned short* __restrict__ Vt,
        float* __restrict__ out) {
    __shared__ unsigned short smem[25600];       // [2][K 4096 | V 4096] | Ps 9216
    unsigned short* Ps = smem + 16384;           // [4 waves][32 q][72 k]

    const int t    = threadIdx.x;
    const int wave = t >> 6;
    const int lane = t & 63;
    const int col  = lane & 15;
    const int quad = lane >> 4;

    // XCD-grouping swizzle (bijective over the 1024-block grid):
    // hardware linear wgid = y*8+x round-robins XCDs; give each XCD 16 bh
    // and all 8 q-blocks of each, so K/V panels are reused within one L2.
    const int lin = blockIdx.y * 8 + blockIdx.x; // 0..1023
    const int xcd = lin & 7;
    const int idx = lin >> 3;                    // 0..127
    const int qb  = idx >> 4;                    // 0..7
    const int bh  = xcd * 16 + (idx & 15);       // 0..127

    const size_t base64 = (size_t)bh * 1024 * 64;
    const int q0w = qb * 128 + wave * 32;

    // Q as B-operand frags: bq[g][h], rows q0w + g*16 + col
    bf16x8 bq[2][2];
    #pragma unroll
    for (int g = 0; g < 2; g++) {
        const unsigned short* qrow = Qt + base64 + (size_t)(q0w + g * 16 + col) * 64;
        bq[g][0] = *(const bf16x8*)(qrow + quad * 8);
        bq[g][1] = *(const bf16x8*)(qrow + 32 + quad * 8);
    }

    const bf16x8 ones = (bf16x8){0x3F80, 0x3F80, 0x3F80, 0x3F80,
                                 0x3F80, 0x3F80, 0x3F80, 0x3F80};

    f32x4 o[2][4];                               // [q-group][d-subtile]
    #pragma unroll
    for (int g = 0; g < 2; g++)
        #pragma unroll
        for (int d = 0; d < 4; d++) o[g][d] = (f32x4){0.f, 0.f, 0.f, 0.f};
    f32x4 osum[2];
    osum[0] = (f32x4){0.f, 0.f, 0.f, 0.f};
    osum[1] = (f32x4){0.f, 0.f, 0.f, 0.f};

    const unsigned short* kg0 = Kt + base64;
    const unsigned short* vg  = Vt + base64;
    unsigned short* Pw = Ps + wave * 32 * 72;

    // ---- prologue: stage tile 0 -> buf0 ----
    #pragma unroll
    for (int j = 0; j < 2; j++) {
        int i = wave + j * 4;                    // instr 0..7
        int G = SWZ(i * 64 + lane);
        gl_lds16(kg0 + (size_t)G * 8, smem + i * 512);
        int p = G >> 3, q = G & 7;
        gl_lds16(vg + (size_t)p * 1024 + q * 8, smem + 4096 + i * 512);
    }
    asm volatile("s_waitcnt vmcnt(0)" ::: "memory");
    __builtin_amdgcn_s_barrier();
    asm volatile("" ::: "memory");

    int cur = 0;
    for (int kt = 0; kt < 16; kt++) {
        // ---- issue next tile's DMA first: latency hides under this compute ----
        if (kt < 15) {
            const unsigned short* kg = kg0 + (size_t)(kt + 1) * 4096;
            unsigned short* Kb = smem + (cur ^ 1) * 8192;
            #pragma unroll
            for (int j = 0; j < 2; j++) {
                int i = wave + j * 4;
                int G = SWZ(i * 64 + lane);
                gl_lds16(kg + (size_t)G * 8, Kb + i * 512);
                int p = G >> 3, q = G & 7;
                gl_lds16(vg + (size_t)p * 1024 + (kt + 1) * 64 + q * 8,
                         Kb + 4096 + i * 512);
            }
        }

        const unsigned short* Ksb = smem + cur * 8192;
        const unsigned short* Vsb = Ksb + 4096;

        // ---- K A-frags (shared across both q-groups) ----
        bf16x8 ak[4][2];
        #pragma unroll
        for (int sub = 0; sub < 4; sub++) {
            int rk = sub * 16 + col;
            ak[sub][0] = *(const bf16x8*)&Ksb[SWZ(rk * 8 + quad) * 8];
            ak[sub][1] = *(const bf16x8*)&Ksb[SWZ(rk * 8 + 4 + quad) * 8];
        }
        // ---- V A-frags (independent: issue early, overlap QK) ----
        bf16x8 av[4][2];
        #pragma unroll
        for (int dsub = 0; dsub < 4; dsub++) {
            int rd = dsub * 16 + col;
            av[dsub][0] = *(const bf16x8*)&Vsb[SWZ(rd * 8 + quad) * 8];
            av[dsub][1] = *(const bf16x8*)&Vsb[SWZ(rd * 8 + 4 + quad) * 8];
        }

        // ---- S^T = K Q^T ; p = 2^s ; packed transpose store ----
        #pragma unroll
        for (int g = 0; g < 2; g++) {
            #pragma unroll
            for (int sub = 0; sub < 4; sub++) {
                f32x4 a = (f32x4){0.f, 0.f, 0.f, 0.f};
                __builtin_amdgcn_s_setprio(1);
                a = __builtin_amdgcn_mfma_f32_16x16x32_bf16(ak[sub][0], bq[g][0], a, 0, 0, 0);
                a = __builtin_amdgcn_mfma_f32_16x16x32_bf16(ak[sub][1], bq[g][1], a, 0, 0, 0);
                __builtin_amdgcn_s_setprio(0);
                // p = exp2(s); lane rows are k = sub*16 + quad*4 + r
                unsigned int u[4];
                #pragma unroll
                for (int r = 0; r < 4; r++) {
                    union { float f; unsigned int u; } c;
                    c.f = exp2f(a[r]);
                    u[r] = c.u;
                }
                if (kt == 15 && sub == 3 && quad == 3) {  // mask keys 1022,1023
                    u[2] = 0; u[3] = 0;
                }
                uint2 pk;
                pk.x = (u[0] >> 16) | (u[1] & 0xFFFF0000u);
                pk.y = (u[2] >> 16) | (u[3] & 0xFFFF0000u);
                *(uint2*)&Pw[(g * 16 + col) * 72 + sub * 16 + quad * 4] = pk;
            }
        }

        // ---- O += V P ; rowsums via ones-MFMA ----
        #pragma unroll
        for (int g = 0; g < 2; g++) {
            bf16x8 bp0 = *(const bf16x8*)&Pw[(g * 16 + col) * 72 + quad * 8];
            bf16x8 bp1 = *(const bf16x8*)&Pw[(g * 16 + col) * 72 + 32 + quad * 8];
            __builtin_amdgcn_s_setprio(1);
            #pragma unroll
            for (int dsub = 0; dsub < 4; dsub++) {
                o[g][dsub] = __builtin_amdgcn_mfma_f32_16x16x32_bf16(av[dsub][0], bp0, o[g][dsub], 0, 0, 0);
                o[g][dsub] = __builtin_amdgcn_mfma_f32_16x16x32_bf16(av[dsub][1], bp1, o[g][dsub], 0, 0, 0);
            }
            osum[g] = __builtin_amdgcn_mfma_f32_16x16x32_bf16(ones, bp0, osum[g], 0, 0, 0);
            osum[g] = __builtin_amdgcn_mfma_f32_16x16x32_bf16(ones, bp1, osum[g], 0, 0, 0);
            __builtin_amdgcn_s_setprio(0);
        }

        // ---- single barrier per tile: prefetch landed + all reads retired ----
        asm volatile("s_waitcnt vmcnt(0)" ::: "memory");
        __builtin_amdgcn_s_barrier();
        asm volatile("" ::: "memory");
        cur ^= 1;
    }

    // ---- epilogue: out[bh*64 + d][q] = o / rowsum ----
    // D layout: col = n = q (within group), rows m = d = dsub*16 + quad*4 + r
    #pragma unroll
    for (int g = 0; g < 2; g++) {
        int q = q0w + g * 16 + col;
        if (q < LP) {
            float inv = 1.0f / osum[g][0];       // all rows identical
            #pragma unroll
            for (int dsub = 0; dsub < 4; dsub++) {
                #pragma unroll
                for (int r = 0; r < 4; r++) {
                    int d = dsub * 16 + quad * 4 + r;
                    out[((size_t)bh * 64 + d) * LP + q] = o[g][dsub][r] * inv;
                }
            }
        }
    }
}

// ---------------------------------------------------------------------------
extern "C" void kernel_launch(void* const* d_in, const int* in_sizes, int n_in,
                              void* d_out, int out_size, void* d_ws, size_t ws_size,
                              hipStream_t stream) {
    const float* x  = (const float*)d_in[0];
    const float* w0 = (const float*)d_in[1];
    const float* b0 = (const float*)d_in[2];
    const float* w1 = (const float*)d_in[3];
    const float* b1 = (const float*)d_in[4];
    const float* w2 = (const float*)d_in[5];
    const float* b2 = (const float*)d_in[6];
    float* out = (float*)d_out;

    // workspace (ushort units): xb 8388608 | wb 2359296 | Qt/Kt/Vt 8388608 each
    unsigned short* xbp = (unsigned short*)d_ws;
    unsigned short* wbp = xbp + 8388608;
    unsigned short* Qt  = wbp + 2359296;
    unsigned short* Kt  = Qt + 8388608;
    unsigned short* Vt  = Kt + 8388608;

    // 1/sqrt(512) * log2(e): softmax computed as 2^s
    const float scale = 0.06375870864f;

    xb_cvt_kernel<<<dim3(16, 8, 16), 256, 0, stream>>>(x, xbp);
    wb_cvt_kernel<<<dim3(3072, 3), 256, 0, stream>>>(w0, w1, w2, wbp);
    conv_mfma_kernel<<<dim3(8, 12, 16), 256, 0, stream>>>(xbp, wbp, b0, b1, b2,
                                                          Qt, Kt, Vt, scale);
    attn_kernel<<<dim3(8, 128), 256, 0, stream>>>(Qt, Kt, Vt, out);
}